// Round 1
// baseline (4096.508 us; speedup 1.0000x reference)
//
#include <hip/hip_runtime.h>
#include <math.h>

// ---------------------------------------------------------------------------
// GraphSAGE fraud detector, fp32 reference-faithful implementation.
// Pipeline:
//   1) deg[dst] += 1                    (atomics)  -> invdeg = 1/max(deg,1)
//   2) s1[dst] += x[src]                (atomics, 128 f32/edge)
//   3) h1 = relu([x | s1*invdeg] @ W1^T + b1)      (tiled fp32 GEMM, mode 0)
//   4) s2[dst] += h1[src]               (atomics, 512 f32/edge)
//   5) logit[r] += sum_c relu([h1 | s2*invdeg] @ W2^T + b2)[r,c] * Wo[c]
//                                        (tiled fp32 GEMM, mode 1, fused head)
//   6) out = sigmoid(logit + bo)
// ---------------------------------------------------------------------------

static inline int ceil_div(int a, int b) { return (a + b - 1) / b; }

__global__ void deg_kernel(const int* __restrict__ dst, float* __restrict__ deg, int E) {
    int e = blockIdx.x * 256 + threadIdx.x;
    if (e < E) atomicAdd(&deg[dst[e]], 1.0f);
}

__global__ void invdeg_kernel(float* __restrict__ deg, int N) {
    int i = blockIdx.x * 256 + threadIdx.x;
    if (i < N) deg[i] = 1.0f / fmaxf(deg[i], 1.0f);
}

// one wave per edge, 128 floats/edge -> 2 floats/lane
__global__ void scatter_f128(const int* __restrict__ src, const int* __restrict__ dst,
                             const float* __restrict__ feat, float* __restrict__ acc, int E) {
    int w = (blockIdx.x * blockDim.x + threadIdx.x) >> 6;
    int lane = threadIdx.x & 63;
    if (w >= E) return;
    int s = src[w], d = dst[w];
    float2 v = ((const float2*)(feat + (size_t)s * 128))[lane];
    float* p = acc + (size_t)d * 128 + lane * 2;
    atomicAdd(p + 0, v.x);
    atomicAdd(p + 1, v.y);
}

// one wave per edge, 512 floats/edge -> 8 floats/lane
__global__ void scatter_f512(const int* __restrict__ src, const int* __restrict__ dst,
                             const float* __restrict__ feat, float* __restrict__ acc, int E) {
    int w = (blockIdx.x * blockDim.x + threadIdx.x) >> 6;
    int lane = threadIdx.x & 63;
    if (w >= E) return;
    int s = src[w], d = dst[w];
    const float4* vp = (const float4*)(feat + (size_t)s * 512);
    float4 v0 = vp[lane];
    float4 v1 = vp[lane + 64];
    float* p = acc + (size_t)d * 512 + 4 * lane;
    atomicAdd(p + 0, v0.x);
    atomicAdd(p + 1, v0.y);
    atomicAdd(p + 2, v0.z);
    atomicAdd(p + 3, v0.w);
    p += 256;
    atomicAdd(p + 0, v1.x);
    atomicAdd(p + 1, v1.y);
    atomicAdd(p + 2, v1.z);
    atomicAdd(p + 3, v1.w);
}

// C = relu([A0 | A1*invdeg] @ W^T + b)
// mode 0: store C[N,Ccols] to out
// mode 1: logit[row] += sum_col C[row,col] * Wo[col]   (h2 never materialized)
// Block: 256 threads (16x16), tile 64x64, thread computes 4x4, BK=32.
__global__ __launch_bounds__(256) void gemm_cat(
    const float* __restrict__ A0,      // [N, K0]
    const float* __restrict__ A1,      // [N, K1], scaled by invdeg[row]
    const float* __restrict__ invdeg,  // [N]
    const float* __restrict__ W,       // [C, K0+K1] row-major
    const float* __restrict__ b,       // [C]
    float* __restrict__ out,           // [N, C] (mode 0)
    const float* __restrict__ Wo,      // [C]    (mode 1)
    float* __restrict__ logit,         // [N]    (mode 1)
    int N, int K0, int K1, int C, int mode)
{
    const int K = K0 + K1;
    __shared__ float As[32][68];   // [k][m], pad 68 -> float4-aligned rows
    __shared__ float Ws[32][68];   // [k][c]
    __shared__ float lred[64];

    const int tid = threadIdx.x;
    const int tx = tid & 15;
    const int ty = tid >> 4;
    const int row0 = blockIdx.x * 64;
    const int col0 = blockIdx.y * 64;

    // staging-load assignment: 2048 floats per tile / 256 threads = 8 each
    const int lm = tid >> 2;          // 0..63 : row (A) or col (W) within tile
    const int lk = (tid & 3) * 8;     // 0,8,16,24 : k offset within tile

    const int arow = row0 + lm;
    const bool arow_ok = arow < N;
    const float inv = arow_ok ? invdeg[arow] : 0.0f;

    float acc[4][4] = {};

    for (int k0 = 0; k0 < K; k0 += 32) {
        float av[8];
        if (arow_ok) {
            int gk = k0 + lk;
            // K0 is a multiple of 32 => branch is uniform over the block
            if (gk < K0) {
                const float4* p = (const float4*)(A0 + (size_t)arow * K0 + gk);
                float4 v0 = p[0], v1 = p[1];
                av[0] = v0.x; av[1] = v0.y; av[2] = v0.z; av[3] = v0.w;
                av[4] = v1.x; av[5] = v1.y; av[6] = v1.z; av[7] = v1.w;
            } else {
                const float4* p = (const float4*)(A1 + (size_t)arow * K1 + (gk - K0));
                float4 v0 = p[0], v1 = p[1];
                av[0] = v0.x * inv; av[1] = v0.y * inv; av[2] = v0.z * inv; av[3] = v0.w * inv;
                av[4] = v1.x * inv; av[5] = v1.y * inv; av[6] = v1.z * inv; av[7] = v1.w * inv;
            }
        } else {
            #pragma unroll
            for (int j = 0; j < 8; ++j) av[j] = 0.0f;
        }
        const float4* wp = (const float4*)(W + (size_t)(col0 + lm) * K + k0 + lk);
        float4 w0 = wp[0], w1 = wp[1];

        __syncthreads();   // previous iteration's reads done before overwrite
        #pragma unroll
        for (int j = 0; j < 8; ++j) As[lk + j][lm] = av[j];
        Ws[lk + 0][lm] = w0.x; Ws[lk + 1][lm] = w0.y;
        Ws[lk + 2][lm] = w0.z; Ws[lk + 3][lm] = w0.w;
        Ws[lk + 4][lm] = w1.x; Ws[lk + 5][lm] = w1.y;
        Ws[lk + 6][lm] = w1.z; Ws[lk + 7][lm] = w1.w;
        __syncthreads();

        #pragma unroll
        for (int kk = 0; kk < 32; ++kk) {
            float4 a = *(const float4*)&As[kk][ty * 4];
            float4 w = *(const float4*)&Ws[kk][tx * 4];
            acc[0][0] += a.x * w.x; acc[0][1] += a.x * w.y; acc[0][2] += a.x * w.z; acc[0][3] += a.x * w.w;
            acc[1][0] += a.y * w.x; acc[1][1] += a.y * w.y; acc[1][2] += a.y * w.z; acc[1][3] += a.y * w.w;
            acc[2][0] += a.z * w.x; acc[2][1] += a.z * w.y; acc[2][2] += a.z * w.z; acc[2][3] += a.z * w.w;
            acc[3][0] += a.w * w.x; acc[3][1] += a.w * w.y; acc[3][2] += a.w * w.z; acc[3][3] += a.w * w.w;
        }
    }

    if (mode == 0) {
        #pragma unroll
        for (int i = 0; i < 4; ++i) {
            int r = row0 + ty * 4 + i;
            if (r < N) {
                int c = col0 + tx * 4;
                float4 v;
                v.x = fmaxf(acc[i][0] + b[c + 0], 0.0f);
                v.y = fmaxf(acc[i][1] + b[c + 1], 0.0f);
                v.z = fmaxf(acc[i][2] + b[c + 2], 0.0f);
                v.w = fmaxf(acc[i][3] + b[c + 3], 0.0f);
                *(float4*)(out + (size_t)r * C + c) = v;
            }
        }
    } else {
        float bw[4], wo[4];
        #pragma unroll
        for (int j = 0; j < 4; ++j) {
            int c = col0 + tx * 4 + j;
            bw[j] = b[c];
            wo[j] = Wo[c];
        }
        float part[4];
        #pragma unroll
        for (int i = 0; i < 4; ++i) {
            float s = 0.0f;
            #pragma unroll
            for (int j = 0; j < 4; ++j)
                s += fmaxf(acc[i][j] + bw[j], 0.0f) * wo[j];
            part[i] = s;
        }
        if (tid < 64) lred[tid] = 0.0f;
        __syncthreads();
        #pragma unroll
        for (int i = 0; i < 4; ++i) atomicAdd(&lred[ty * 4 + i], part[i]);
        __syncthreads();
        if (tid < 64 && row0 + tid < N) atomicAdd(&logit[row0 + tid], lred[tid]);
    }
}

__global__ void head_kernel(const float* __restrict__ logit, const float* __restrict__ bo,
                            float* __restrict__ out, int N) {
    int i = blockIdx.x * 256 + threadIdx.x;
    if (i < N) out[i] = 1.0f / (1.0f + expf(-(logit[i] + bo[0])));
}

extern "C" void kernel_launch(void* const* d_in, const int* in_sizes, int n_in,
                              void* d_out, int out_size, void* d_ws, size_t ws_size,
                              hipStream_t stream) {
    const float* x  = (const float*)d_in[0];
    const int*   ei = (const int*)d_in[1];
    const float* W1 = (const float*)d_in[2];
    const float* b1 = (const float*)d_in[3];
    const float* W2 = (const float*)d_in[4];
    const float* b2 = (const float*)d_in[5];
    const float* Wo = (const float*)d_in[6];
    const float* bo = (const float*)d_in[7];
    float* out = (float*)d_out;

    const int N = in_sizes[0] / 128;   // 50000
    const int E = in_sizes[1] / 2;     // 400000
    const int* src = ei;
    const int* dst = ei + E;

    // workspace layout (256B-aligned regions)
    char* ws = (char*)d_ws;
    size_t off = 0;
    auto alloc = [&](size_t bytes) {
        void* p = ws + off;
        off += (bytes + 255) & ~(size_t)255;
        return p;
    };
    float* invdeg = (float*)alloc((size_t)N * 4);
    float* logit  = (float*)alloc((size_t)N * 4);
    float* s1     = (float*)alloc((size_t)N * 128 * 4);
    float* h1     = (float*)alloc((size_t)N * 512 * 4);
    float* s2     = (float*)alloc((size_t)N * 512 * 4);
    (void)ws_size; (void)n_in; (void)out_size;

    hipMemsetAsync(invdeg, 0, (size_t)N * 4, stream);
    hipMemsetAsync(logit,  0, (size_t)N * 4, stream);
    hipMemsetAsync(s1,     0, (size_t)N * 128 * 4, stream);
    hipMemsetAsync(s2,     0, (size_t)N * 512 * 4, stream);

    deg_kernel<<<ceil_div(E, 256), 256, 0, stream>>>(dst, invdeg, E);
    invdeg_kernel<<<ceil_div(N, 256), 256, 0, stream>>>(invdeg, N);

    // layer 1 aggregation + GEMM
    scatter_f128<<<ceil_div(E * 64, 256), 256, 0, stream>>>(src, dst, x, s1, E);
    dim3 g1(ceil_div(N, 64), 512 / 64);
    gemm_cat<<<g1, 256, 0, stream>>>(x, s1, invdeg, W1, b1, h1, nullptr, nullptr,
                                     N, 128, 128, 512, 0);

    // layer 2 aggregation + GEMM with fused output head
    scatter_f512<<<ceil_div(E * 64, 256), 256, 0, stream>>>(src, dst, h1, s2, E);
    gemm_cat<<<g1, 256, 0, stream>>>(h1, s2, invdeg, W2, b2, nullptr, Wo, logit,
                                     N, 512, 512, 512, 1);

    head_kernel<<<ceil_div(N, 256), 256, 0, stream>>>(logit, bo, out, N);
}

// Round 2
// 1329.517 us; speedup vs baseline: 3.0812x; 3.0812x over previous
//
#include <hip/hip_runtime.h>
#include <math.h>

// ---------------------------------------------------------------------------
// GraphSAGE fraud detector, fp32, CSR-gather aggregation (no feature atomics).
// Pipeline:
//   1) deg[dst]++ (int histogram) -> rowstart = exclusive scan (1-block scan)
//      -> bucket fill: ebuf[rowstart[dst] + cursor[dst]++] = src
//   2) n1 = gather-mean of x over incoming edges        (gather, 128 f32/row)
//   3) h1 = relu([x | n1] @ W1^T + b1)                  (tiled fp32 GEMM)
//   4) n2 = gather-mean of h1                           (gather, 512 f32/row)
//   5) logit[r] = sum_c relu([h1 | n2] @ W2^T + b2)[r,c] * Wo[c]  (fused GEMM)
//   6) out = sigmoid(logit + bo)
// ---------------------------------------------------------------------------

static inline int ceil_div(int a, int b) { return (a + b - 1) / b; }

__global__ void hist_kernel(const int* __restrict__ dst, int* __restrict__ deg, int E) {
    int e = blockIdx.x * 256 + threadIdx.x;
    if (e < E) atomicAdd(&deg[dst[e]], 1);
}

// single-block exclusive scan over deg[N] -> rowstart[N+1]
__global__ __launch_bounds__(1024) void scan_kernel(const int* __restrict__ deg,
                                                    int* __restrict__ rowstart, int N) {
    __shared__ int sdata[1024];
    __shared__ int running;
    if (threadIdx.x == 0) running = 0;
    __syncthreads();
    for (int base = 0; base < N; base += 1024) {
        int i = base + threadIdx.x;
        int v = (i < N) ? deg[i] : 0;
        sdata[threadIdx.x] = v;
        __syncthreads();
        #pragma unroll
        for (int off = 1; off < 1024; off <<= 1) {
            int t = (threadIdx.x >= off) ? sdata[threadIdx.x - off] : 0;
            __syncthreads();
            sdata[threadIdx.x] += t;
            __syncthreads();
        }
        if (i < N) rowstart[i] = running + sdata[threadIdx.x] - v;
        __syncthreads();
        if (threadIdx.x == 1023) running += sdata[1023];
        __syncthreads();
    }
    if (threadIdx.x == 0) rowstart[N] = running;   // == E
}

__global__ void copy_kernel(const int* __restrict__ a, int* __restrict__ b, int N) {
    int i = blockIdx.x * 256 + threadIdx.x;
    if (i < N) b[i] = a[i];
}

__global__ void bucket_kernel(const int* __restrict__ src, const int* __restrict__ dst,
                              int* __restrict__ cursor, int* __restrict__ ebuf, int E) {
    int e = blockIdx.x * 256 + threadIdx.x;
    if (e < E) {
        int pos = atomicAdd(&cursor[dst[e]], 1);
        ebuf[pos] = src[e];
    }
}

// one wave per dst row; 128 f32/row -> float2 per lane
__global__ void gather_mean_128(const int* __restrict__ rowstart, const int* __restrict__ ebuf,
                                const float* __restrict__ feat, float* __restrict__ out, int N) {
    int w = (blockIdx.x * blockDim.x + threadIdx.x) >> 6;
    int lane = threadIdx.x & 63;
    if (w >= N) return;
    int e0 = rowstart[w], e1 = rowstart[w + 1];
    float2 acc = {0.0f, 0.0f};
    for (int i = e0; i < e1; ++i) {
        int s = ebuf[i];
        float2 v = ((const float2*)(feat + (size_t)s * 128))[lane];
        acc.x += v.x; acc.y += v.y;
    }
    float inv = 1.0f / fmaxf((float)(e1 - e0), 1.0f);
    acc.x *= inv; acc.y *= inv;
    ((float2*)(out + (size_t)w * 128))[lane] = acc;
}

// one wave per dst row; 512 f32/row -> 2x float4 per lane
__global__ void gather_mean_512(const int* __restrict__ rowstart, const int* __restrict__ ebuf,
                                const float* __restrict__ feat, float* __restrict__ out, int N) {
    int w = (blockIdx.x * blockDim.x + threadIdx.x) >> 6;
    int lane = threadIdx.x & 63;
    if (w >= N) return;
    int e0 = rowstart[w], e1 = rowstart[w + 1];
    float4 a0 = {0, 0, 0, 0}, a1 = {0, 0, 0, 0};
    for (int i = e0; i < e1; ++i) {
        int s = ebuf[i];
        const float4* p = (const float4*)(feat + (size_t)s * 512);
        float4 v0 = p[lane];
        float4 v1 = p[lane + 64];
        a0.x += v0.x; a0.y += v0.y; a0.z += v0.z; a0.w += v0.w;
        a1.x += v1.x; a1.y += v1.y; a1.z += v1.z; a1.w += v1.w;
    }
    float inv = 1.0f / fmaxf((float)(e1 - e0), 1.0f);
    a0.x *= inv; a0.y *= inv; a0.z *= inv; a0.w *= inv;
    a1.x *= inv; a1.y *= inv; a1.z *= inv; a1.w *= inv;
    float4* q = (float4*)(out + (size_t)w * 512);
    q[lane] = a0;
    q[lane + 64] = a1;
}

// C = relu([A0 | A1] @ W^T + b)
// mode 0: store C[N,Ccols] to out
// mode 1: logit[row] += sum_col C[row,col] * Wo[col]   (h2 never materialized)
// Block: 256 threads (16x16), tile 64x64, thread computes 4x4, BK=32.
__global__ __launch_bounds__(256) void gemm_cat(
    const float* __restrict__ A0,      // [N, K0]
    const float* __restrict__ A1,      // [N, K1] (already normalized mean)
    const float* __restrict__ W,       // [C, K0+K1] row-major
    const float* __restrict__ b,       // [C]
    float* __restrict__ out,           // [N, C] (mode 0)
    const float* __restrict__ Wo,      // [C]    (mode 1)
    float* __restrict__ logit,         // [N]    (mode 1)
    int N, int K0, int K1, int C, int mode)
{
    const int K = K0 + K1;
    __shared__ float As[32][68];   // [k][m], pad 68 -> float4-aligned rows
    __shared__ float Ws[32][68];   // [k][c]
    __shared__ float lred[64];

    const int tid = threadIdx.x;
    const int tx = tid & 15;
    const int ty = tid >> 4;
    const int row0 = blockIdx.x * 64;
    const int col0 = blockIdx.y * 64;

    // staging-load assignment: 2048 floats per tile / 256 threads = 8 each
    const int lm = tid >> 2;          // 0..63 : row (A) or col (W) within tile
    const int lk = (tid & 3) * 8;     // 0,8,16,24 : k offset within tile

    const int arow = row0 + lm;
    const bool arow_ok = arow < N;

    float acc[4][4] = {};

    for (int k0 = 0; k0 < K; k0 += 32) {
        float av[8];
        if (arow_ok) {
            int gk = k0 + lk;
            // K0 is a multiple of 32 => branch is uniform over the block
            if (gk < K0) {
                const float4* p = (const float4*)(A0 + (size_t)arow * K0 + gk);
                float4 v0 = p[0], v1 = p[1];
                av[0] = v0.x; av[1] = v0.y; av[2] = v0.z; av[3] = v0.w;
                av[4] = v1.x; av[5] = v1.y; av[6] = v1.z; av[7] = v1.w;
            } else {
                const float4* p = (const float4*)(A1 + (size_t)arow * K1 + (gk - K0));
                float4 v0 = p[0], v1 = p[1];
                av[0] = v0.x; av[1] = v0.y; av[2] = v0.z; av[3] = v0.w;
                av[4] = v1.x; av[5] = v1.y; av[6] = v1.z; av[7] = v1.w;
            }
        } else {
            #pragma unroll
            for (int j = 0; j < 8; ++j) av[j] = 0.0f;
        }
        const float4* wp = (const float4*)(W + (size_t)(col0 + lm) * K + k0 + lk);
        float4 w0 = wp[0], w1 = wp[1];

        __syncthreads();   // previous iteration's reads done before overwrite
        #pragma unroll
        for (int j = 0; j < 8; ++j) As[lk + j][lm] = av[j];
        Ws[lk + 0][lm] = w0.x; Ws[lk + 1][lm] = w0.y;
        Ws[lk + 2][lm] = w0.z; Ws[lk + 3][lm] = w0.w;
        Ws[lk + 4][lm] = w1.x; Ws[lk + 5][lm] = w1.y;
        Ws[lk + 6][lm] = w1.z; Ws[lk + 7][lm] = w1.w;
        __syncthreads();

        #pragma unroll
        for (int kk = 0; kk < 32; ++kk) {
            float4 a = *(const float4*)&As[kk][ty * 4];
            float4 w = *(const float4*)&Ws[kk][tx * 4];
            acc[0][0] += a.x * w.x; acc[0][1] += a.x * w.y; acc[0][2] += a.x * w.z; acc[0][3] += a.x * w.w;
            acc[1][0] += a.y * w.x; acc[1][1] += a.y * w.y; acc[1][2] += a.y * w.z; acc[1][3] += a.y * w.w;
            acc[2][0] += a.z * w.x; acc[2][1] += a.z * w.y; acc[2][2] += a.z * w.z; acc[2][3] += a.z * w.w;
            acc[3][0] += a.w * w.x; acc[3][1] += a.w * w.y; acc[3][2] += a.w * w.z; acc[3][3] += a.w * w.w;
        }
    }

    if (mode == 0) {
        #pragma unroll
        for (int i = 0; i < 4; ++i) {
            int r = row0 + ty * 4 + i;
            if (r < N) {
                int c = col0 + tx * 4;
                float4 v;
                v.x = fmaxf(acc[i][0] + b[c + 0], 0.0f);
                v.y = fmaxf(acc[i][1] + b[c + 1], 0.0f);
                v.z = fmaxf(acc[i][2] + b[c + 2], 0.0f);
                v.w = fmaxf(acc[i][3] + b[c + 3], 0.0f);
                *(float4*)(out + (size_t)r * C + c) = v;
            }
        }
    } else {
        float bw[4], wo[4];
        #pragma unroll
        for (int j = 0; j < 4; ++j) {
            int c = col0 + tx * 4 + j;
            bw[j] = b[c];
            wo[j] = Wo[c];
        }
        float part[4];
        #pragma unroll
        for (int i = 0; i < 4; ++i) {
            float s = 0.0f;
            #pragma unroll
            for (int j = 0; j < 4; ++j)
                s += fmaxf(acc[i][j] + bw[j], 0.0f) * wo[j];
            part[i] = s;
        }
        if (tid < 64) lred[tid] = 0.0f;
        __syncthreads();
        #pragma unroll
        for (int i = 0; i < 4; ++i) atomicAdd(&lred[ty * 4 + i], part[i]);
        __syncthreads();
        if (tid < 64 && row0 + tid < N) atomicAdd(&logit[row0 + tid], lred[tid]);
    }
}

__global__ void head_kernel(const float* __restrict__ logit, const float* __restrict__ bo,
                            float* __restrict__ out, int N) {
    int i = blockIdx.x * 256 + threadIdx.x;
    if (i < N) out[i] = 1.0f / (1.0f + expf(-(logit[i] + bo[0])));
}

extern "C" void kernel_launch(void* const* d_in, const int* in_sizes, int n_in,
                              void* d_out, int out_size, void* d_ws, size_t ws_size,
                              hipStream_t stream) {
    const float* x  = (const float*)d_in[0];
    const int*   ei = (const int*)d_in[1];
    const float* W1 = (const float*)d_in[2];
    const float* b1 = (const float*)d_in[3];
    const float* W2 = (const float*)d_in[4];
    const float* b2 = (const float*)d_in[5];
    const float* Wo = (const float*)d_in[6];
    const float* bo = (const float*)d_in[7];
    float* out = (float*)d_out;

    const int N = in_sizes[0] / 128;   // 50000
    const int E = in_sizes[1] / 2;     // 400000
    const int* src = ei;
    const int* dst = ei + E;

    // workspace layout (256B-aligned regions)
    char* ws = (char*)d_ws;
    size_t off = 0;
    auto alloc = [&](size_t bytes) {
        void* p = ws + off;
        off += (bytes + 255) & ~(size_t)255;
        return p;
    };
    int* deg      = (int*)alloc((size_t)N * 4);
    int* rowstart = (int*)alloc((size_t)(N + 1) * 4);
    int* cursor   = (int*)alloc((size_t)N * 4);
    int* ebuf     = (int*)alloc((size_t)E * 4);
    float* logit  = (float*)alloc((size_t)N * 4);
    float* n1     = (float*)alloc((size_t)N * 128 * 4);
    float* h1     = (float*)alloc((size_t)N * 512 * 4);
    float* n2     = (float*)alloc((size_t)N * 512 * 4);
    (void)ws_size; (void)n_in; (void)out_size;

    hipMemsetAsync(deg,   0, (size_t)N * 4, stream);
    hipMemsetAsync(logit, 0, (size_t)N * 4, stream);

    // CSR build
    hist_kernel<<<ceil_div(E, 256), 256, 0, stream>>>(dst, deg, E);
    scan_kernel<<<1, 1024, 0, stream>>>(deg, rowstart, N);
    copy_kernel<<<ceil_div(N, 256), 256, 0, stream>>>(rowstart, cursor, N);
    bucket_kernel<<<ceil_div(E, 256), 256, 0, stream>>>(src, dst, cursor, ebuf, E);

    // layer 1: gather + GEMM
    gather_mean_128<<<ceil_div(N * 64, 256), 256, 0, stream>>>(rowstart, ebuf, x, n1, N);
    dim3 g1(ceil_div(N, 64), 512 / 64);
    gemm_cat<<<g1, 256, 0, stream>>>(x, n1, W1, b1, h1, nullptr, nullptr,
                                     N, 128, 128, 512, 0);

    // layer 2: gather + GEMM with fused output head
    gather_mean_512<<<ceil_div(N * 64, 256), 256, 0, stream>>>(rowstart, ebuf, h1, n2, N);
    gemm_cat<<<g1, 256, 0, stream>>>(h1, n2, W2, b2, nullptr, Wo, logit,
                                     N, 512, 512, 512, 1);

    head_kernel<<<ceil_div(N, 256), 256, 0, stream>>>(logit, bo, out, N);
}

// Round 3
// 487.435 us; speedup vs baseline: 8.4042x; 2.7276x over previous
//
#include <hip/hip_runtime.h>
#include <math.h>

// ---------------------------------------------------------------------------
// GraphSAGE fraud detector. CSR-gather aggregation + bf16 MFMA GEMMs.
//   1) CSR build (hist -> scan -> bucket)
//   2) xb = bf16(x); W1b = bf16(W1); W2b = bf16(W2)
//   3) n1b = gather-mean(x) -> bf16
//   4) h1b = relu([xb|n1b] @ W1b^T + b1)   MFMA, bf16 out    (mode 0)
//   5) n2b = gather-mean(h1b) -> bf16
//   6) logit = relu([h1b|n2b] @ W2b^T + b2) @ Wo             (mode 1, fused)
//   7) out = sigmoid(logit + bo)
// MFMA 16x16x32 bf16: A-frag A[m=lane&15][k=quad*8+j]; C/D col=lane&15,
// row=quad*4+reg (m89/m97-verified layouts).
// ---------------------------------------------------------------------------

typedef __attribute__((ext_vector_type(8))) short bf16x8;   // 8 bf16, 4 VGPRs
typedef __attribute__((ext_vector_type(4))) float f32x4;

static inline int ceil_div(int a, int b) { return (a + b - 1) / b; }

__device__ inline float bf2f_lo(unsigned u) { return __builtin_bit_cast(float, u << 16); }
__device__ inline float bf2f_hi(unsigned u) { return __builtin_bit_cast(float, u & 0xffff0000u); }
__device__ inline unsigned f2bf(float f) {   // RNE round to bf16, return bits in low 16
    unsigned u = __builtin_bit_cast(unsigned, f);
    u += 0x7fffu + ((u >> 16) & 1u);
    return u >> 16;
}

// ---------------- CSR build ----------------

__global__ void hist_kernel(const int* __restrict__ dst, int* __restrict__ deg, int E) {
    int e = blockIdx.x * 256 + threadIdx.x;
    if (e < E) atomicAdd(&deg[dst[e]], 1);
}

__global__ __launch_bounds__(1024) void scan_kernel(const int* __restrict__ deg,
                                                    int* __restrict__ rowstart, int N) {
    __shared__ int sdata[1024];
    __shared__ int running;
    if (threadIdx.x == 0) running = 0;
    __syncthreads();
    for (int base = 0; base < N; base += 1024) {
        int i = base + threadIdx.x;
        int v = (i < N) ? deg[i] : 0;
        sdata[threadIdx.x] = v;
        __syncthreads();
        for (int off = 1; off < 1024; off <<= 1) {
            int t = (threadIdx.x >= off) ? sdata[threadIdx.x - off] : 0;
            __syncthreads();
            sdata[threadIdx.x] += t;
            __syncthreads();
        }
        if (i < N) rowstart[i] = running + sdata[threadIdx.x] - v;
        __syncthreads();
        if (threadIdx.x == 1023) running += sdata[1023];
        __syncthreads();
    }
    if (threadIdx.x == 0) rowstart[N] = running;
}

__global__ void copy_kernel(const int* __restrict__ a, int* __restrict__ b, int N) {
    int i = blockIdx.x * 256 + threadIdx.x;
    if (i < N) b[i] = a[i];
}

__global__ void bucket_kernel(const int* __restrict__ src, const int* __restrict__ dst,
                              int* __restrict__ cursor, int* __restrict__ ebuf, int E) {
    int e = blockIdx.x * 256 + threadIdx.x;
    if (e < E) {
        int pos = atomicAdd(&cursor[dst[e]], 1);
        ebuf[pos] = src[e];
    }
}

// ---------------- dtype conversion ----------------

// n4 = element_count/4; in/out element counts are multiples of 4
__global__ void cvt_bf16_kernel(const float* __restrict__ in, unsigned short* __restrict__ out, int n4) {
    int i = blockIdx.x * 256 + threadIdx.x;
    if (i < n4) {
        float4 v = ((const float4*)in)[i];
        ushort4 o;
        o.x = (unsigned short)f2bf(v.x);
        o.y = (unsigned short)f2bf(v.y);
        o.z = (unsigned short)f2bf(v.z);
        o.w = (unsigned short)f2bf(v.w);
        ((ushort4*)out)[i] = o;
    }
}

// ---------------- gather means ----------------

// one wave per dst row; fp32 x [N,128] -> bf16 mean [N,128]
__global__ void gather_mean_128(const int* __restrict__ rowstart, const int* __restrict__ ebuf,
                                const float* __restrict__ feat, unsigned short* __restrict__ outb, int N) {
    int w = (blockIdx.x * blockDim.x + threadIdx.x) >> 6;
    int lane = threadIdx.x & 63;
    if (w >= N) return;
    int e0 = rowstart[w], e1 = rowstart[w + 1];
    float ax = 0.0f, ay = 0.0f;
    for (int i = e0; i < e1; ++i) {
        int s = ebuf[i];
        float2 v = ((const float2*)(feat + (size_t)s * 128))[lane];
        ax += v.x; ay += v.y;
    }
    float inv = 1.0f / fmaxf((float)(e1 - e0), 1.0f);
    unsigned lo = f2bf(ax * inv), hi = f2bf(ay * inv);
    ((unsigned*)outb)[(size_t)w * 64 + lane] = lo | (hi << 16);
}

// one wave per dst row; bf16 feat [N,512] -> bf16 mean [N,512]; fp32 accum
__global__ void gather_mean_512(const int* __restrict__ rowstart, const int* __restrict__ ebuf,
                                const unsigned short* __restrict__ featb,
                                unsigned short* __restrict__ outb, int N) {
    int w = (blockIdx.x * blockDim.x + threadIdx.x) >> 6;
    int lane = threadIdx.x & 63;
    if (w >= N) return;
    int e0 = rowstart[w], e1 = rowstart[w + 1];
    float a[8] = {0, 0, 0, 0, 0, 0, 0, 0};
    const uint4* base = (const uint4*)featb;     // 512 bf16/row = 64 uint4/row
    for (int i = e0; i < e1; ++i) {
        int s = ebuf[i];
        uint4 v = base[(size_t)s * 64 + lane];
        a[0] += bf2f_lo(v.x); a[1] += bf2f_hi(v.x);
        a[2] += bf2f_lo(v.y); a[3] += bf2f_hi(v.y);
        a[4] += bf2f_lo(v.z); a[5] += bf2f_hi(v.z);
        a[6] += bf2f_lo(v.w); a[7] += bf2f_hi(v.w);
    }
    float inv = 1.0f / fmaxf((float)(e1 - e0), 1.0f);
    uint4 o;
    o.x = f2bf(a[0] * inv) | (f2bf(a[1] * inv) << 16);
    o.y = f2bf(a[2] * inv) | (f2bf(a[3] * inv) << 16);
    o.z = f2bf(a[4] * inv) | (f2bf(a[5] * inv) << 16);
    o.w = f2bf(a[6] * inv) | (f2bf(a[7] * inv) << 16);
    ((uint4*)outb)[(size_t)w * 64 + lane] = o;
}

// ---------------- bf16 MFMA GEMM ----------------
// C = relu([A0b | A1b] @ Wb^T + b)
// mode 0: store C as bf16 to outb [N, C]
// mode 1: logit[row] += sum_col C[row,col] * Wo[col]
// Block 256 thr = 4 waves (2x2); tile 128x128; wave tile 64x64 (4x4 mfma); BK=32.
__global__ __launch_bounds__(256) void gemm_mfma(
    const unsigned short* __restrict__ A0,   // [N, K0] bf16
    const unsigned short* __restrict__ A1,   // [N, K1] bf16
    const unsigned short* __restrict__ W,    // [C, K0+K1] bf16 row-major
    const float* __restrict__ b,             // [C] fp32
    unsigned short* __restrict__ outb,       // [N, C] bf16 (mode 0)
    const float* __restrict__ Wo,            // [C] fp32    (mode 1)
    float* __restrict__ logit,               // [N] fp32    (mode 1)
    int N, int K0, int K1, int C, int mode)
{
    const int K = K0 + K1;
    // row stride 40 shorts = 80 B (16B-aligned, lane stride 20 dwords -> 2-way, free)
    __shared__ short As[128 * 40];
    __shared__ short Bs[128 * 40];

    const int tid  = threadIdx.x;
    const int lane = tid & 63;
    const int wave = tid >> 6;
    const int wm = wave & 1, wn = wave >> 1;
    const int cl = lane & 15, quad = lane >> 4;
    const int row0 = blockIdx.x * 128;
    const int col0 = blockIdx.y * 128;

    // staging: thread t loads 16 bf16 of one row-half (k offset shalf*16)
    const int srow  = tid >> 1;     // 0..127
    const int shalf = tid & 1;      // 0/1
    const int arow = row0 + srow;
    const bool aok = arow < N;
    const int wcol = col0 + srow;   // always < C here (C multiple of 128)

    f32x4 acc[4][4];
    #pragma unroll
    for (int mt = 0; mt < 4; ++mt)
        #pragma unroll
        for (int nt = 0; nt < 4; ++nt)
            acc[mt][nt] = (f32x4){0.f, 0.f, 0.f, 0.f};

    for (int k0 = 0; k0 < K; k0 += 32) {
        const int gk = k0 + shalf * 16;
        uint4 av0 = {0, 0, 0, 0}, av1 = {0, 0, 0, 0};
        if (aok) {
            if (gk < K0) {      // block-uniform (K0, k0 multiples of 32)
                const uint4* p = (const uint4*)(A0 + (size_t)arow * K0 + gk);
                av0 = p[0]; av1 = p[1];
            } else {
                const uint4* p = (const uint4*)(A1 + (size_t)arow * K1 + (gk - K0));
                av0 = p[0]; av1 = p[1];
            }
        }
        const uint4* wp = (const uint4*)(W + (size_t)wcol * K + gk);
        uint4 wv0 = wp[0], wv1 = wp[1];

        __syncthreads();    // previous iteration's frag reads done
        *(uint4*)&As[srow * 40 + shalf * 16 + 0] = av0;
        *(uint4*)&As[srow * 40 + shalf * 16 + 8] = av1;
        *(uint4*)&Bs[srow * 40 + shalf * 16 + 0] = wv0;
        *(uint4*)&Bs[srow * 40 + shalf * 16 + 8] = wv1;
        __syncthreads();

        bf16x8 af[4], bfr[4];
        #pragma unroll
        for (int mt = 0; mt < 4; ++mt)
            af[mt] = *(const bf16x8*)&As[(wm * 64 + mt * 16 + cl) * 40 + quad * 8];
        #pragma unroll
        for (int nt = 0; nt < 4; ++nt)
            bfr[nt] = *(const bf16x8*)&Bs[(wn * 64 + nt * 16 + cl) * 40 + quad * 8];

        #pragma unroll
        for (int mt = 0; mt < 4; ++mt)
            #pragma unroll
            for (int nt = 0; nt < 4; ++nt)
                acc[mt][nt] = __builtin_amdgcn_mfma_f32_16x16x32_bf16(
                    af[mt], bfr[nt], acc[mt][nt], 0, 0, 0);
    }

    if (mode == 0) {
        #pragma unroll
        for (int nt = 0; nt < 4; ++nt) {
            const int colb = col0 + wn * 64 + nt * 16 + cl;
            const float bb = b[colb];
            #pragma unroll
            for (int mt = 0; mt < 4; ++mt) {
                #pragma unroll
                for (int r = 0; r < 4; ++r) {
                    int row = row0 + wm * 64 + mt * 16 + quad * 4 + r;
                    if (row < N)
                        outb[(size_t)row * C + colb] =
                            (unsigned short)f2bf(fmaxf(acc[mt][nt][r] + bb, 0.0f));
                }
            }
        }
    } else {
        float bv[4], wv[4];
        #pragma unroll
        for (int nt = 0; nt < 4; ++nt) {
            const int colb = col0 + wn * 64 + nt * 16 + cl;
            bv[nt] = b[colb];
            wv[nt] = Wo[colb];
        }
        #pragma unroll
        for (int mt = 0; mt < 4; ++mt) {
            #pragma unroll
            for (int r = 0; r < 4; ++r) {
                float s = 0.0f;
                #pragma unroll
                for (int nt = 0; nt < 4; ++nt)
                    s += fmaxf(acc[mt][nt][r] + bv[nt], 0.0f) * wv[nt];
                s += __shfl_xor(s, 1);
                s += __shfl_xor(s, 2);
                s += __shfl_xor(s, 4);
                s += __shfl_xor(s, 8);
                int row = row0 + wm * 64 + mt * 16 + quad * 4 + r;
                if (cl == 0 && row < N) atomicAdd(&logit[row], s);
            }
        }
    }
}

__global__ void head_kernel(const float* __restrict__ logit, const float* __restrict__ bo,
                            float* __restrict__ out, int N) {
    int i = blockIdx.x * 256 + threadIdx.x;
    if (i < N) out[i] = 1.0f / (1.0f + expf(-(logit[i] + bo[0])));
}

extern "C" void kernel_launch(void* const* d_in, const int* in_sizes, int n_in,
                              void* d_out, int out_size, void* d_ws, size_t ws_size,
                              hipStream_t stream) {
    const float* x  = (const float*)d_in[0];
    const int*   ei = (const int*)d_in[1];
    const float* W1 = (const float*)d_in[2];
    const float* b1 = (const float*)d_in[3];
    const float* W2 = (const float*)d_in[4];
    const float* b2 = (const float*)d_in[5];
    const float* Wo = (const float*)d_in[6];
    const float* bo = (const float*)d_in[7];
    float* out = (float*)d_out;

    const int N = in_sizes[0] / 128;   // 50000
    const int E = in_sizes[1] / 2;     // 400000
    const int* src = ei;
    const int* dst = ei + E;

    char* ws = (char*)d_ws;
    size_t off = 0;
    auto alloc = [&](size_t bytes) {
        void* p = ws + off;
        off += (bytes + 255) & ~(size_t)255;
        return p;
    };
    int* deg      = (int*)alloc((size_t)N * 4);
    int* rowstart = (int*)alloc((size_t)(N + 1) * 4);
    int* cursor   = (int*)alloc((size_t)N * 4);
    int* ebuf     = (int*)alloc((size_t)E * 4);
    float* logit  = (float*)alloc((size_t)N * 4);
    unsigned short* xb  = (unsigned short*)alloc((size_t)N * 128 * 2);
    unsigned short* W1b = (unsigned short*)alloc((size_t)512 * 256 * 2);
    unsigned short* W2b = (unsigned short*)alloc((size_t)512 * 1024 * 2);
    unsigned short* n1b = (unsigned short*)alloc((size_t)N * 128 * 2);
    unsigned short* h1b = (unsigned short*)alloc((size_t)N * 512 * 2);
    unsigned short* n2b = (unsigned short*)alloc((size_t)N * 512 * 2);
    (void)ws_size; (void)n_in; (void)out_size;

    hipMemsetAsync(deg,   0, (size_t)N * 4, stream);
    hipMemsetAsync(logit, 0, (size_t)N * 4, stream);

    // conversions
    cvt_bf16_kernel<<<ceil_div(N * 128 / 4, 256), 256, 0, stream>>>(x, xb, N * 128 / 4);
    cvt_bf16_kernel<<<ceil_div(512 * 256 / 4, 256), 256, 0, stream>>>(W1, W1b, 512 * 256 / 4);
    cvt_bf16_kernel<<<ceil_div(512 * 1024 / 4, 256), 256, 0, stream>>>(W2, W2b, 512 * 1024 / 4);

    // CSR build
    hist_kernel<<<ceil_div(E, 256), 256, 0, stream>>>(dst, deg, E);
    scan_kernel<<<1, 1024, 0, stream>>>(deg, rowstart, N);
    copy_kernel<<<ceil_div(N, 256), 256, 0, stream>>>(rowstart, cursor, N);
    bucket_kernel<<<ceil_div(E, 256), 256, 0, stream>>>(src, dst, cursor, ebuf, E);

    dim3 gg(ceil_div(N, 128), 512 / 128);

    // layer 1
    gather_mean_128<<<ceil_div(N * 64, 256), 256, 0, stream>>>(rowstart, ebuf, x, n1b, N);
    gemm_mfma<<<gg, 256, 0, stream>>>(xb, n1b, W1b, b1, h1b, nullptr, nullptr,
                                      N, 128, 128, 512, 0);

    // layer 2 + fused head
    gather_mean_512<<<ceil_div(N * 64, 256), 256, 0, stream>>>(rowstart, ebuf, h1b, n2b, N);
    gemm_mfma<<<gg, 256, 0, stream>>>(h1b, n2b, W2b, b2, nullptr, Wo, logit,
                                      N, 512, 512, 512, 1);

    head_kernel<<<ceil_div(N, 256), 256, 0, stream>>>(logit, bo, out, N);
}